// Round 12
// baseline (147.096 us; speedup 1.0000x reference)
//
#include <hip/hip_runtime.h>
#include <hip/hip_bf16.h>
#include <stdint.h>

typedef __hip_bfloat16 bf16;
typedef __attribute__((ext_vector_type(8))) __bf16 frag8;
typedef __attribute__((ext_vector_type(4))) float f32x4;

// ---------------- helpers ----------------
__device__ inline float wred_sum(float v) {
#pragma unroll
  for (int o = 32; o; o >>= 1) v += __shfl_down(v, o);
  return v;
}
__device__ inline float wred_max(float v) {
#pragma unroll
  for (int o = 32; o; o >>= 1) v = fmaxf(v, __shfl_down(v, o));
  return v;
}
__device__ inline unsigned short bits_of(bf16 h) { return *(unsigned short*)&h; }
__device__ inline frag8 cvt8(float4 lo, float4 hi) {
  union { frag8 f; unsigned short u[8]; } r;
  r.u[0] = bits_of(__float2bfloat16(lo.x));
  r.u[1] = bits_of(__float2bfloat16(lo.y));
  r.u[2] = bits_of(__float2bfloat16(lo.z));
  r.u[3] = bits_of(__float2bfloat16(lo.w));
  r.u[4] = bits_of(__float2bfloat16(hi.x));
  r.u[5] = bits_of(__float2bfloat16(hi.y));
  r.u[6] = bits_of(__float2bfloat16(hi.z));
  r.u[7] = bits_of(__float2bfloat16(hi.w));
  return r.f;
}

// ---------------- 1. W[256][768] f32 -> Wt[768][256] bf16 ----------------------
__global__ __launch_bounds__(256) void wt_k(const float* __restrict__ W,
                                            bf16* __restrict__ Wt) {
  __shared__ float t[32][33];
  int c0 = blockIdx.x * 32, o0 = blockIdx.y * 32;
  int tx = threadIdx.x & 31, ty = threadIdx.x >> 5;
#pragma unroll
  for (int i = 0; i < 4; ++i)
    t[ty + i * 8][tx] = W[(long)(o0 + ty + i * 8) * 768 + c0 + tx];
  __syncthreads();
#pragma unroll
  for (int i = 0; i < 4; ++i)
    Wt[(long)(c0 + ty + i * 8) * 256 + o0 + tx] = __float2bfloat16(t[tx][ty + i * 8]);
}

// ---------------- 2. small barrier-free GEMM, one wave per 64x16 tile ----------
template <bool AF32, bool BF32, bool BIAS>
__global__ __launch_bounds__(64) void gemm_sm2(const void* __restrict__ Av,
                                               const void* __restrict__ Bv,
                                               float* __restrict__ C, int K, int ldc,
                                               const float* __restrict__ bias) {
  int n0 = blockIdx.x * 16, m0 = blockIdx.y * 64;
  int lr = threadIdx.x & 15, kg = threadIdx.x >> 4;
  f32x4 acc[4] = {};
#pragma unroll 2
  for (int k0 = 0; k0 < K; k0 += 32) {
    frag8 af[4], bv;
#pragma unroll
    for (int mi = 0; mi < 4; ++mi) {
      long row = m0 + mi * 16 + lr;
      if constexpr (AF32) {
        const float* ap = (const float*)Av + row * K + k0 + kg * 8;
        af[mi] = cvt8(*(const float4*)ap, *(const float4*)(ap + 4));
      } else {
        af[mi] = *(const frag8*)((const bf16*)Av + row * K + k0 + kg * 8);
      }
    }
    {
      long row = n0 + lr;
      if constexpr (BF32) {
        const float* bp = (const float*)Bv + row * K + k0 + kg * 8;
        bv = cvt8(*(const float4*)bp, *(const float4*)(bp + 4));
      } else {
        bv = *(const frag8*)((const bf16*)Bv + row * K + k0 + kg * 8);
      }
    }
#pragma unroll
    for (int mi = 0; mi < 4; ++mi)
      acc[mi] = __builtin_amdgcn_mfma_f32_16x16x32_bf16(af[mi], bv, acc[mi], 0, 0, 0);
  }
#pragma unroll
  for (int mi = 0; mi < 4; ++mi)
#pragma unroll
    for (int j = 0; j < 4; ++j) {
      int row = m0 + mi * 16 + kg * 4 + j;
      int col = n0 + lr;
      float v = acc[mi][j];
      if (BIAS) v += bias[col];
      C[(long)row * ldc + col] = v;
    }
}

// ---------------- 3. logits2: 16 c-chunks of 48; 320 thr, 1 quad/thread --------
// Bias term (emb.conv_b const over p) drops out of softmax (shift-invariance).
__global__ __launch_bounds__(320) void logits2(const float* __restrict__ X,
                                               const float* __restrict__ embW,
                                               float* __restrict__ lgt) {
  int cs = blockIdx.x, b = blockIdx.y;
  __shared__ float e[12 * 48];   // 2.3 KB
  for (int i = threadIdx.x; i < 12 * 48; i += 320)
    e[i] = embW[((long)b * 12 + i / 48) * 768 + cs * 48 + (i % 48)];
  __syncthreads();
  int slot = threadIdx.x;
  if (slot >= 301) return;
  int p = slot * 4;
  const float* xb = X + ((long)b * 768 + cs * 48) * 1204 + p;
  float a0[12], a1[12], a2[12], a3[12];
#pragma unroll
  for (int n = 0; n < 12; ++n) { a0[n] = a1[n] = a2[n] = a3[n] = 0.f; }
#pragma unroll 4
  for (int c = 0; c < 48; ++c) {
    float4 xq = *(const float4*)(xb + (long)c * 1204);
#pragma unroll
    for (int n = 0; n < 12; ++n) {
      float en = e[n * 48 + c];
      a0[n] += en * xq.x; a1[n] += en * xq.y;
      a2[n] += en * xq.z; a3[n] += en * xq.w;
    }
  }
#pragma unroll
  for (int n = 0; n < 12; ++n)
    *(float4*)&lgt[((long)cs * 384 + b * 12 + n) * 1204 + p] =
        make_float4(a0[n], a1[n], a2[n], a3[n]);
}

// ---------------- 4. softmax (16 partials) -> am [32][16][1280] bf16 zero-pad --
__global__ __launch_bounds__(256) void softmax2(const float* __restrict__ lgt,
                                                bf16* __restrict__ am) {
  const long PS = (long)384 * 1204;
  int b = blockIdx.x, n = blockIdx.y, tid = threadIdx.x;
  bf16* row = am + ((long)b * 16 + n) * 1280;
  if (n >= 12) {
    for (int i = tid; i < 1280; i += 256) row[i] = __float2bfloat16(0.f);
    return;
  }
  const float* l0 = lgt + ((long)b * 12 + n) * 1204;
  float vals[5];
  float m = -3.0e38f;
#pragma unroll
  for (int i = 0; i < 5; ++i) {
    int pp = tid + i * 256;
    if (pp < 1204) {
      float v = 0.f;
#pragma unroll
      for (int q = 0; q < 16; ++q) v += l0[q * PS + pp];
      vals[i] = v;
    } else {
      vals[i] = -3.0e38f;
    }
    m = fmaxf(m, vals[i]);
  }
  m = wred_max(m);
  __shared__ float rd[4];
  int w = tid >> 6, lane = tid & 63;
  if (lane == 0) rd[w] = m;
  __syncthreads();
  m = fmaxf(fmaxf(rd[0], rd[1]), fmaxf(rd[2], rd[3]));
  float s = 0.f;
#pragma unroll
  for (int i = 0; i < 5; ++i) {
    int pp = tid + i * 256;
    vals[i] = (pp < 1204) ? __expf(vals[i] - m) : 0.f;
    s += vals[i];
  }
  s = wred_sum(s);
  __syncthreads();
  if (lane == 0) rd[w] = s;
  __syncthreads();
  s = rd[0] + rd[1] + rd[2] + rd[3];
  float inv = 1.f / s;
#pragma unroll
  for (int i = 0; i < 5; ++i) {
    int pp = tid + i * 256;
    row[pp] = __float2bfloat16((pp < 1204) ? vals[i] * inv : 0.f);
  }
}

// ---------------- 5. ctx_a: Yp[kc][b][n][c] = sum_{p in chunk} X[b][c][p]A[n][p]
__global__ __launch_bounds__(64) void ctx_a(const float* __restrict__ X,
                                            const bf16* __restrict__ am,
                                            float* __restrict__ Yp) {
  int ct = blockIdx.x, kc = blockIdx.y, b = blockIdx.z;
  int c0 = ct * 64;
  int kst = kc * 256, kend = min(kst + 256, 1204);
  int lr = threadIdx.x & 15, kg = threadIdx.x >> 4;
  f32x4 acc[4] = {};
  for (int k0 = kst; k0 < kend; k0 += 32) {
    frag8 bv = *(const frag8*)(am + ((long)b * 16 + lr) * 1280 + k0 + kg * 8);
    bool full = (k0 + 32 <= 1204);
#pragma unroll
    for (int mi = 0; mi < 4; ++mi) {
      const float* ap = X + ((long)b * 768 + c0 + mi * 16 + lr) * 1204 + k0 + kg * 8;
      frag8 av;
      if (full) {
        av = cvt8(*(const float4*)ap, *(const float4*)(ap + 4));
      } else {
        float t[8];
#pragma unroll
        for (int j = 0; j < 8; ++j)
          t[j] = (k0 + kg * 8 + j < 1204) ? ap[j] : 0.f;   // A=0 there anyway
        av = cvt8(make_float4(t[0], t[1], t[2], t[3]),
                  make_float4(t[4], t[5], t[6], t[7]));
      }
      acc[mi] = __builtin_amdgcn_mfma_f32_16x16x32_bf16(av, bv, acc[mi], 0, 0, 0);
    }
  }
  if (lr < 12) {
#pragma unroll
    for (int mi = 0; mi < 4; ++mi) {
      long base = (((long)kc * 32 + b) * 12 + lr) * 768 + c0 + mi * 16 + kg * 4;
      *(float4*)&Yp[base] = make_float4(acc[mi][0], acc[mi][1], acc[mi][2], acc[mi][3]);
    }
  }
}

// ---------------- 6. red_y: Ysum[i] = sum_{q<5} Yp[q][i], bf16 out -------------
__global__ __launch_bounds__(256) void red_y(const float* __restrict__ Yp,
                                             bf16* __restrict__ Ysum) {
  const long QS = (long)32 * 12 * 768;   // 294912
  long i = ((long)blockIdx.x * 256 + threadIdx.x) * 4;
  if (i >= QS) return;
  float4 v = *(const float4*)(Yp + i);
#pragma unroll
  for (int q = 1; q < 5; ++q) {
    float4 u = *(const float4*)(Yp + q * QS + i);
    v.x += u.x; v.y += u.y; v.z += u.z; v.w += u.w;
  }
  union { ushort4 s; bf16 h[4]; } o;
  o.h[0] = __float2bfloat16(v.x);
  o.h[1] = __float2bfloat16(v.y);
  o.h[2] = __float2bfloat16(v.z);
  o.h[3] = __float2bfloat16(v.w);
  *(ushort4*)(Ysum + i) = o.s;
}

// ---------------- 7. tail_k: ctx GEMM + LN1 + FFN1 + FFN2 + LN2 fused ----------
// 24 blocks x 16 rows, 256 threads (4 waves, wave w owns cols w*64..+63).
// All LDS rows padded (+8 bf16 / +4 f32) -> 2-way bank aliasing only (free).
__global__ __launch_bounds__(256) void tail_k(
    const bf16* __restrict__ Ysum, const float* __restrict__ convw,
    const float* __restrict__ convb, const float* __restrict__ emb,
    const float* __restrict__ ln1g, const float* __restrict__ ln1b,
    const float* __restrict__ w1, const float* __restrict__ b1,
    const float* __restrict__ w2, const float* __restrict__ b2,
    const float* __restrict__ ln2g, const float* __restrict__ ln2b,
    float* __restrict__ out) {
  int r0 = blockIdx.x * 16;
  __shared__ __align__(16) bf16 A_l[16][776];    // Ysum rows (24.8 KB)
  __shared__ float x_l[16][260];                 // LN1 out f32 (residual)
  __shared__ __align__(16) bf16 xb_l[16][264];   // LN1 out bf16
  __shared__ __align__(16) bf16 h1_l[16][264];   // FFN1 out
  int tid = threadIdx.x;
  int lane = tid & 63, w = tid >> 6;
  int lr = lane & 15, kg = lane >> 4;
  int n0 = w * 64;
  // Phase A: stage Ysum rows into LDS (coalesced 16B chunks)
  for (int i = tid; i < 1536; i += 256) {        // 96 x 16B per row
    int r = i / 96, c8 = (i % 96) * 8;
    *(uint4*)&A_l[r][c8] = *(const uint4*)(Ysum + (long)(r0 + r) * 768 + c8);
  }
  __syncthreads();
  // Phase B: ctx = Ysum @ convw^T  (M=16, N=256, K=768)
  {
    f32x4 acc[4] = {};
    for (int k0 = 0; k0 < 768; k0 += 32) {
      frag8 af = *(const frag8*)&A_l[lr][k0 + kg * 8];
#pragma unroll
      for (int ni = 0; ni < 4; ++ni) {
        const float* bp = convw + (long)(n0 + ni * 16 + lr) * 768 + k0 + kg * 8;
        frag8 bv = cvt8(*(const float4*)bp, *(const float4*)(bp + 4));
        acc[ni] = __builtin_amdgcn_mfma_f32_16x16x32_bf16(af, bv, acc[ni], 0, 0, 0);
      }
    }
#pragma unroll
    for (int ni = 0; ni < 4; ++ni)
#pragma unroll
      for (int j = 0; j < 4; ++j) {
        int row = kg * 4 + j, col = n0 + ni * 16 + lr;
        x_l[row][col] = acc[ni][j] + convb[col] + emb[(long)(r0 + row) * 256 + col];
      }
  }
  __syncthreads();
  // LN1 (per-row over 256; 16 threads/row, shfl_xor reduce within 16-lane group)
  {
    int r = tid >> 4, seg = tid & 15;
    float s = 0.f, s2 = 0.f;
#pragma unroll
    for (int i = 0; i < 16; ++i) {
      float v = x_l[r][seg * 16 + i];
      s += v; s2 += v * v;
    }
#pragma unroll
    for (int msk = 1; msk < 16; msk <<= 1) {
      s += __shfl_xor(s, msk);
      s2 += __shfl_xor(s2, msk);
    }
    float mean = s * (1.f / 256.f);
    float var = s2 * (1.f / 256.f) - mean * mean;
    float rs = rsqrtf(var + 1e-5f);
#pragma unroll
    for (int i = 0; i < 16; ++i) {
      int c = seg * 16 + i;
      float y = (x_l[r][c] - mean) * rs * ln1g[c] + ln1b[c];
      x_l[r][c] = y;
      xb_l[r][c] = __float2bfloat16(y);
    }
  }
  __syncthreads();
  // Phase C: FFN1 = relu(xb @ w1^T + b1)  (K=256)
  {
    f32x4 acc[4] = {};
    for (int k0 = 0; k0 < 256; k0 += 32) {
      frag8 af = *(const frag8*)&xb_l[lr][k0 + kg * 8];
#pragma unroll
      for (int ni = 0; ni < 4; ++ni) {
        const float* bp = w1 + (long)(n0 + ni * 16 + lr) * 256 + k0 + kg * 8;
        frag8 bv = cvt8(*(const float4*)bp, *(const float4*)(bp + 4));
        acc[ni] = __builtin_amdgcn_mfma_f32_16x16x32_bf16(af, bv, acc[ni], 0, 0, 0);
      }
    }
#pragma unroll
    for (int ni = 0; ni < 4; ++ni)
#pragma unroll
      for (int j = 0; j < 4; ++j) {
        int row = kg * 4 + j, col = n0 + ni * 16 + lr;
        h1_l[row][col] = __float2bfloat16(fmaxf(acc[ni][j] + b1[col], 0.f));
      }
  }
  __syncthreads();
  // Phase D: FFN2 + residual  (K=256)
  {
    f32x4 acc[4] = {};
    for (int k0 = 0; k0 < 256; k0 += 32) {
      frag8 af = *(const frag8*)&h1_l[lr][k0 + kg * 8];
#pragma unroll
      for (int ni = 0; ni < 4; ++ni) {
        const float* bp = w2 + (long)(n0 + ni * 16 + lr) * 256 + k0 + kg * 8;
        frag8 bv = cvt8(*(const float4*)bp, *(const float4*)(bp + 4));
        acc[ni] = __builtin_amdgcn_mfma_f32_16x16x32_bf16(af, bv, acc[ni], 0, 0, 0);
      }
    }
#pragma unroll
    for (int ni = 0; ni < 4; ++ni)
#pragma unroll
      for (int j = 0; j < 4; ++j) {
        int row = kg * 4 + j, col = n0 + ni * 16 + lr;
        x_l[row][col] += acc[ni][j] + b2[col];   // own element: read+write safe
      }
  }
  __syncthreads();
  // LN2 -> out
  {
    int r = tid >> 4, seg = tid & 15;
    float s = 0.f, s2 = 0.f;
#pragma unroll
    for (int i = 0; i < 16; ++i) {
      float v = x_l[r][seg * 16 + i];
      s += v; s2 += v * v;
    }
#pragma unroll
    for (int msk = 1; msk < 16; msk <<= 1) {
      s += __shfl_xor(s, msk);
      s2 += __shfl_xor(s2, msk);
    }
    float mean = s * (1.f / 256.f);
    float var = s2 * (1.f / 256.f) - mean * mean;
    float rs = rsqrtf(var + 1e-5f);
#pragma unroll
    for (int i = 0; i < 16; ++i) {
      int c = seg * 16 + i;
      out[(long)(r0 + r) * 256 + c] = (x_l[r][c] - mean) * rs * ln2g[c] + ln2b[c];
    }
  }
}

// ---------------- launcher -----------------------------------------------------
extern "C" void kernel_launch(void* const* d_in, const int* in_sizes, int n_in,
                              void* d_out, int out_size, void* d_ws, size_t ws_size,
                              hipStream_t stream) {
  const float* roi   = (const float*)d_in[0];
  const float* imgf  = (const float*)d_in[1];
  const float* convw = (const float*)d_in[2];
  const float* convb = (const float*)d_in[3];
  const float* embw  = (const float*)d_in[4];
  const float* embb  = (const float*)d_in[5];
  const float* ln1g  = (const float*)d_in[6];
  const float* ln1b  = (const float*)d_in[7];
  const float* w1    = (const float*)d_in[8];
  const float* b1    = (const float*)d_in[9];
  const float* w2    = (const float*)d_in[10];
  const float* b2    = (const float*)d_in[11];
  const float* ln2g  = (const float*)d_in[12];
  const float* ln2b  = (const float*)d_in[13];
  float* out = (float*)d_out;

  char* p = (char*)d_ws;
  size_t off = 0;
  auto take = [&](size_t sz) -> char* {
    char* r = p + off;
    off += (sz + 255) & ~(size_t)255;
    return r;
  };
  float* emb  = (float*)take((size_t)384 * 256 * 4);
  bf16*  Wt   = (bf16*)take((size_t)768 * 256 * 2);
  float* embW = (float*)take((size_t)384 * 768 * 4);
  float* lgt  = (float*)take((size_t)16 * 384 * 1204 * 4);   // 29.6 MB
  bf16*  am   = (bf16*)take((size_t)32 * 16 * 1280 * 2);
  float* Yp   = (float*)take((size_t)5 * 32 * 12 * 768 * 4);
  bf16*  Ysum = (bf16*)take((size_t)384 * 768 * 2);

  // 1. emb = roi @ embw^T + embb   [384][256] fp32   (96 blocks)
  gemm_sm2<true, true, true><<<dim3(16, 6), 64, 0, stream>>>(
      roi, embw, emb, 1024, 256, embb);
  // 2. Wt = conv_w^T (bf16)       [768][256]
  wt_k<<<dim3(24, 8), 256, 0, stream>>>(convw, Wt);
  // 3. embW = emb @ conv_w        [384][768] fp32   (288 blocks)
  gemm_sm2<true, false, false><<<dim3(48, 6), 64, 0, stream>>>(
      emb, Wt, embW, 256, 768, nullptr);
  // 4. logits partials: 16 c-chunks, 320 thr, 1 quad/thread  (512 blocks)
  logits2<<<dim3(16, 32), 320, 0, stream>>>(imgf, embW, lgt);
  // 5. softmax (sums 16 partials) -> am bf16 (rows 12..15 zero)
  softmax2<<<dim3(32, 16), 256, 0, stream>>>(lgt, am);
  // 6. Y partials: Yp[kc][b][n][c] = sum_p X*A  (MFMA, K=p, no transpose)
  ctx_a<<<dim3(12, 5, 32), 64, 0, stream>>>(imgf, am, Yp);
  // 7. Ysum = sum partials -> bf16  (288 blocks, streaming)
  red_y<<<288, 256, 0, stream>>>(Yp, Ysum);
  // 8. fused tail: ctx GEMM + LN1 + FFN1 + FFN2 + LN2 -> out  (24 blocks)
  tail_k<<<24, 256, 0, stream>>>(Ysum, convw, convb, emb, ln1g, ln1b,
                                 w1, b1, w2, b2, ln2g, ln2b, out);
}